// Round 5
// baseline (355.914 us; speedup 1.0000x reference)
//
#include <hip/hip_runtime.h>

// Problem constants: B=1, N=256, C=128, H=4, D=32
#define N 256
#define C 128
#define H 4
#define D 32
#define LN_EPS 1e-5f
#define INFB 1e9f
#define SCALE 0.17677669529663687f  // 1/sqrt(32)

typedef __bf16 bf16x8 __attribute__((ext_vector_type(8)));
typedef __bf16 bf16x2 __attribute__((ext_vector_type(2)));
typedef _Float16 halfx8 __attribute__((ext_vector_type(8)));
typedef _Float16 halfx4 __attribute__((ext_vector_type(4)));
typedef float floatx4 __attribute__((ext_vector_type(4)));

__device__ __forceinline__ floatx4 mfma16(bf16x8 a, bf16x8 b, floatx4 c) {
    return __builtin_amdgcn_mfma_f32_16x16x32_bf16(a, b, c, 0, 0, 0);
}
__device__ __forceinline__ floatx4 mfma16h(halfx8 a, halfx8 b, floatx4 c) {
    return __builtin_amdgcn_mfma_f32_16x16x32_f16(a, b, c, 0, 0, 0);
}

// ---------------------------------------------------------------------------
// K0: weight prep. mats 0..3: wTg[mat][n][c] = (bf16) w[c][n] (transposed).
// mat 4: woh[c][k] = (fp16) wo[c][k] (plain convert, layout kept k-major).
// ---------------------------------------------------------------------------
__global__ __launch_bounds__(256) void wt_kernel(
    const float* __restrict__ wq, const float* __restrict__ wk,
    const float* __restrict__ wv, const float* __restrict__ wg,
    const float* __restrict__ wo, __bf16* __restrict__ wTg,
    _Float16* __restrict__ woh)
{
    const int mat = blockIdx.x >> 3, seg = blockIdx.x & 7;
    if (mat == 4) {
        #pragma unroll
        for (int rep = 0; rep < 8; ++rep) {
            const int idx = seg * 2048 + rep * 256 + threadIdx.x;
            woh[idx] = (_Float16)wo[idx];
        }
        return;
    }
    const float* __restrict__ ws_ = (mat == 0) ? wq : (mat == 1) ? wk
                                  : (mat == 2) ? wv : wg;
    #pragma unroll
    for (int rep = 0; rep < 8; ++rep) {
        const int idx = seg * 2048 + rep * 256 + threadIdx.x;
        const int n = idx >> 7, c = idx & 127;
        wTg[mat * 16384 + n * 128 + c] = (__bf16)ws_[c * 128 + n];
    }
}

// ---------------------------------------------------------------------------
// K1: transpose + LayerNorm -> xn bf16, plus tri-bias.
// xn row r = a*256+b holds LN(x[b,a,:]) = x_t[a,b,:].
// Tri-bias is stored PRE-PERMUTED into attn's SWAPPED-QK S-fragment order:
//   value (h, j=a, k=b) is consumed by attn lane = (j&15) + 16*((k&15)>>2)
//   of j-tile (a>>4), at slot kt*4 + r with kt = k>>4, r = k&3. Each attn
//   lane reads its 64 bias values as 16 contiguous float4s.
// ---------------------------------------------------------------------------
__global__ __launch_bounds__(256) void ln_kernel(
    const float* __restrict__ x, const float* __restrict__ lnw,
    const float* __restrict__ lnb, const float* __restrict__ wbias,
    __bf16* __restrict__ xn, float* __restrict__ tbp)
{
    const int t = threadIdx.x;
    const int wv = t >> 6, lane = t & 63;
    const int r = blockIdx.x * 4 + wv;
    const int a = r >> 8, b = r & 255;   // tb value for (h, j=a, k=b)

    const float2 v = *(const float2*)&x[((size_t)b * N + a) * C + lane * 2];
    float s  = v.x + v.y;
    float ss = v.x * v.x + v.y * v.y;
    #pragma unroll
    for (int o = 32; o; o >>= 1) {
        s  += __shfl_xor(s,  o);
        ss += __shfl_xor(ss, o);
    }
    const float mu  = s * (1.0f / 128.0f);
    const float var = ss * (1.0f / 128.0f) - mu * mu;
    const float rs  = rsqrtf(var + LN_EPS);

    const float2 lw = *(const float2*)&lnw[lane * 2];
    const float2 lb = *(const float2*)&lnb[lane * 2];
    const float y0 = (v.x - mu) * rs * lw.x + lb.x;
    const float y1 = (v.y - mu) * rs * lw.y + lb.y;

    bf16x2 xo; xo[0] = (__bf16)y0; xo[1] = (__bf16)y1;
    *(bf16x2*)&xn[(size_t)r * C + lane * 2] = xo;

    // permuted tb address components for (j=a, k=b), swapped-QK layout
    const int jb   = a >> 4;                             // 16-row j-tile
    const int lnA  = (a & 15) | (((b & 15) >> 2) << 4);  // attn lane
    const int slot = ((b >> 4) << 2) | (b & 3);          // kt*4 + r (r=k&3)
    #pragma unroll
    for (int hh = 0; hh < H; ++hh) {
        const float2 wb2 = *(const float2*)&wbias[hh * C + lane * 2];
        float tv = y0 * wb2.x + y1 * wb2.y;
        #pragma unroll
        for (int o = 32; o; o >>= 1) tv += __shfl_xor(tv, o);
        if (lane == 0)
            tbp[(size_t)(((hh * 16 + jb) * 64 + lnA) * 64 + slot)] = tv;
    }
}

// ---------------------------------------------------------------------------
// K2: projection GEMM [65536x128]x[128x128] per mat (Q,K,V,G). 4 waves in
// 2x2 64x64 tiles; C-tiles round-trip wave-private LDS so global writes are
// 4KB-contiguous. Outputs [i*4+h][row][32] bf16; Q pre-scaled.
// ---------------------------------------------------------------------------
__global__ __launch_bounds__(256, 3) void proj_kernel(
    const __bf16* __restrict__ xn, const __bf16* __restrict__ wTg,
    __bf16* __restrict__ qbuf, __bf16* __restrict__ kbuf,
    __bf16* __restrict__ vbuf, __bf16* __restrict__ gbuf)
{
    __shared__ __bf16 Cs[4][64 * 72];

    const int mat = blockIdx.y;
    const int t = threadIdx.x, w = t >> 6, lane = t & 63;
    const int ln16 = lane & 15, quad = lane >> 4;
    const int wr = w >> 1, wc = w & 1;
    const int m_base = blockIdx.x * 128 + wr * 64;
    const int n_base = wc * 64;
    const __bf16* __restrict__ wT = wTg + mat * 16384;

    floatx4 Cf[4][4];
    const floatx4 z4 = {0.f, 0.f, 0.f, 0.f};
    #pragma unroll
    for (int mt = 0; mt < 4; ++mt)
        #pragma unroll
        for (int nt = 0; nt < 4; ++nt) Cf[mt][nt] = z4;

    #pragma unroll
    for (int ks = 0; ks < 4; ++ks) {
        bf16x8 Af[4], Bf[4];
        #pragma unroll
        for (int mt = 0; mt < 4; ++mt)
            Af[mt] = *(const bf16x8*)&xn[(size_t)(m_base + mt*16 + ln16) * 128 + ks*32 + quad*8];
        #pragma unroll
        for (int nt = 0; nt < 4; ++nt)
            Bf[nt] = *(const bf16x8*)&wT[(n_base + nt*16 + ln16) * 128 + ks*32 + quad*8];
        #pragma unroll
        for (int mt = 0; mt < 4; ++mt)
            #pragma unroll
            for (int nt = 0; nt < 4; ++nt)
                Cf[mt][nt] = mfma16(Af[mt], Bf[nt], Cf[mt][nt]);
    }

    const float scl = (mat == 0) ? SCALE : 1.0f;
    __bf16* __restrict__ Cw = &Cs[w][0];
    #pragma unroll
    for (int mt = 0; mt < 4; ++mt)
        #pragma unroll
        for (int nt = 0; nt < 4; ++nt)
            #pragma unroll
            for (int r = 0; r < 4; ++r)
                Cw[(mt*16 + quad*4 + r) * 72 + nt*16 + ln16] =
                    (__bf16)(Cf[mt][nt][r] * scl);

    __bf16* __restrict__ dst = (mat == 0) ? qbuf : (mat == 1) ? kbuf
                             : (mat == 2) ? vbuf : gbuf;
    const int m = m_base + lane;
    const int i = m >> 8, jk = m & 255;
    #pragma unroll
    for (int hf = 0; hf < 2; ++hf) {
        const int hh = wc * 2 + hf;
        __bf16* __restrict__ drow = dst + (((size_t)i*4 + hh)*256 + jk)*32;
        #pragma unroll
        for (int u = 0; u < 4; ++u)
            *(bf16x8*)&drow[u*8] = *(const bf16x8*)&Cw[lane*72 + hf*32 + u*8];
    }
}

// ---------------------------------------------------------------------------
// K3: MFMA attention, one (i,h) per block. SWAPPED QK^T (S = mfma(K,Q)) so
// each lane owns ONE j-row (j = jrow0+ln16): softmax reduce = 2 shfl_xor
// (16,32) instead of 16; P->PV transpose done IN-REGISTER via 4-lane
// bpermute shuffles — the 33.8 KB Pw LDS buffer is GONE. LDS 72->44 KB
// -> 3 blocks/CU (was 2; latency-bound kernel, occupancy is the lever).
// K stays LDS-staged (R3 lesson: K direct-from-global serializes on L2
// latency, 2x regression). Epilogue keeps coalesced 1KB store via small
// Pe buffer (stride 44 = conflict-free writes).
// Rule #20: all S/U indices compile-time constant (scratch disaster R0).
// ---------------------------------------------------------------------------
__global__ __launch_bounds__(256, 3) void attn_kernel(
    const float* __restrict__ tbp, const float* __restrict__ mask,
    const float* __restrict__ bg,
    const __bf16* __restrict__ qbuf, const __bf16* __restrict__ kbuf,
    const __bf16* __restrict__ vbuf, const __bf16* __restrict__ gbuf,
    _Float16* __restrict__ ogh)
{
    const int bid = blockIdx.x;
    const int i = bid & 255, h = bid >> 8;
    const int t = threadIdx.x, w = t >> 6, lane = t & 63;
    const int ln16 = lane & 15, quad = lane >> 4;

    __shared__ __align__(16) __bf16 Ks[256 * 40];      // 20480 B
    __shared__ __align__(16) __bf16 VT[32 * 264];      // 16896 B
    __shared__ __align__(16) _Float16 Pe[4][16 * 44];  //  5632 B
    __shared__ float mb[256];                          //  1024 B
    // total 44032 B -> 3 blocks/CU

    const size_t hb = (size_t)i * 4 + h;
    const __bf16* __restrict__ qb = qbuf + hb * 8192;
    const __bf16* __restrict__ kb = kbuf + hb * 8192;
    const __bf16* __restrict__ vb = vbuf + hb * 8192;
    const __bf16* __restrict__ gb = gbuf + hb * 8192;

    #pragma unroll
    for (int u = 0; u < 4; ++u)
        *(bf16x8*)&Ks[t * 40 + u * 8] = *(const bf16x8*)&kb[t * 32 + u * 8];
    #pragma unroll
    for (int u = 0; u < 4; ++u) {
        const bf16x8 vv = *(const bf16x8*)&vb[t * 32 + u * 8];
        #pragma unroll
        for (int e = 0; e < 8; ++e) VT[(u*8 + e) * 264 + t] = vv[e];
    }
    mb[t] = INFB * (mask[(size_t)t * N + i] - 1.0f);
    __syncthreads();

    const float bg0 = bg[h*32 + ln16], bg1 = bg[h*32 + 16 + ln16];

    _Float16* __restrict__ Pww = &Pe[w][0];
    const floatx4 z4 = {0.f, 0.f, 0.f, 0.f};
    _Float16* __restrict__ ogb = ogh + ((size_t)h * 256 + i) * 8192;

    const int idxA = ln16 + ((quad & 1) << 5);  // source lane for frag words 0,1
    const int idxB = idxA + 16;                 // source lane for frag words 2,3

    #pragma unroll 1
    for (int jt = 0; jt < 4; ++jt) {
        const int jrow0 = w*64 + jt*16;
        // per-lane contiguous 256B slab of pre-permuted tri-bias
        const float* __restrict__ tbl =
            tbp + ((size_t)((h*16 + (w*4 + jt))*64 + lane) << 6);
        const bf16x8 Qf = *(const bf16x8*)&qb[(jrow0 + ln16)*32 + quad*8];

        // ---- swapped scores: S[kt][r] = score(j = jrow0+ln16,
        //      k = kt*16 + quad*4 + r) ----
        floatx4 S[16];
        #pragma unroll
        for (int kt = 0; kt < 16; ++kt) {
            const bf16x8 Kf = *(const bf16x8*)&Ks[(kt*16 + ln16)*40 + quad*8];
            S[kt] = mfma16(Kf, Qf, z4);
        }

        // ---- bias: mask (LDS float4) + tri-bias (global float4) ----
        #pragma unroll
        for (int kt = 0; kt < 16; ++kt) {
            const float4 tb4 = *(const float4*)&tbl[kt*4];
            const float4 mb4 = *(const float4*)&mb[kt*16 + quad*4];
            S[kt][0] += mb4.x + tb4.x;
            S[kt][1] += mb4.y + tb4.y;
            S[kt][2] += mb4.z + tb4.z;
            S[kt][3] += mb4.w + tb4.w;
        }

        // ---- row softmax: lane-local 64-max/sum + 2 shfl_xor ----
        floatx4 a0 = S[0], a1 = S[1], a2 = S[2], a3 = S[3];
        #pragma unroll
        for (int kt = 4; kt < 16; kt += 4) {
            #pragma unroll
            for (int e = 0; e < 4; ++e) {
                a0[e] = fmaxf(a0[e], S[kt+0][e]);
                a1[e] = fmaxf(a1[e], S[kt+1][e]);
                a2[e] = fmaxf(a2[e], S[kt+2][e]);
                a3[e] = fmaxf(a3[e], S[kt+3][e]);
            }
        }
        float mx;
        {
            floatx4 m01, m23;
            #pragma unroll
            for (int e = 0; e < 4; ++e) { m01[e] = fmaxf(a0[e], a1[e]); m23[e] = fmaxf(a2[e], a3[e]); }
            mx = fmaxf(fmaxf(fmaxf(m01[0], m01[1]), fmaxf(m01[2], m01[3])),
                       fmaxf(fmaxf(m23[0], m23[1]), fmaxf(m23[2], m23[3])));
        }
        mx = fmaxf(mx, __shfl_xor(mx, 16));
        mx = fmaxf(mx, __shfl_xor(mx, 32));

        floatx4 lacc = z4;
        #pragma unroll
        for (int kt = 0; kt < 16; ++kt)
            #pragma unroll
            for (int e = 0; e < 4; ++e) {
                const float p = __expf(S[kt][e] - mx);
                S[kt][e] = p; lacc[e] += p;
            }
        float l = (lacc[0] + lacc[1]) + (lacc[2] + lacc[3]);
        l += __shfl_xor(l, 16);
        l += __shfl_xor(l, 32);

        // ---- pack P to bf16 pairs (lane-local) ----
        unsigned int U0[16], U1[16];
        #pragma unroll
        for (int kt = 0; kt < 16; ++kt) {
            bf16x2 p0, p1;
            p0[0] = (__bf16)S[kt][0]; p0[1] = (__bf16)S[kt][1];
            p1[0] = (__bf16)S[kt][2]; p1[1] = (__bf16)S[kt][3];
            U0[kt] = __builtin_bit_cast(unsigned int, p0);
            U1[kt] = __builtin_bit_cast(unsigned int, p1);
        }

        // ---- PV: in-register 4-lane transpose feeds A-frag directly ----
        floatx4 O0 = z4, O1 = z4;
        #pragma unroll
        for (int ks = 0; ks < 8; ++ks) {
            const unsigned int e0a = __shfl(U0[2*ks],   idxA);
            const unsigned int f0a = __shfl(U0[2*ks+1], idxA);
            const unsigned int e1a = __shfl(U1[2*ks],   idxA);
            const unsigned int f1a = __shfl(U1[2*ks+1], idxA);
            const unsigned int e0b = __shfl(U0[2*ks],   idxB);
            const unsigned int f0b = __shfl(U0[2*ks+1], idxB);
            const unsigned int e1b = __shfl(U1[2*ks],   idxB);
            const unsigned int f1b = __shfl(U1[2*ks+1], idxB);
            uint4 pw;
            pw.x = (quad < 2) ? e0a : f0a;
            pw.y = (quad < 2) ? e1a : f1a;
            pw.z = (quad < 2) ? e0b : f0b;
            pw.w = (quad < 2) ? e1b : f1b;
            const bf16x8 PA = __builtin_bit_cast(bf16x8, pw);
            const bf16x8 V0 = *(const bf16x8*)&VT[ln16*264 + ks*32 + quad*8];
            const bf16x8 V1 = *(const bf16x8*)&VT[(16 + ln16)*264 + ks*32 + quad*8];
            O0 = mfma16(PA, V0, O0);
            O1 = mfma16(PA, V1, O1);
        }

        // ---- normalize+gate -> fp16 repack in wave-private LDS ----
        // O0[r]: j = jrow0 + quad*4 + r, d = ln16 (O1: d = 16+ln16).
        // row-sum l lives at lanes keyed by ln16=j&15 -> fetch via shfl.
        const float invl = 1.0f / l;
        #pragma unroll
        for (int r = 0; r < 4; ++r) {
            const float inv = __shfl(invl, quad*4 + r);
            const int jrow = jrow0 + quad*4 + r;
            const float g0 = (float)gb[jrow*32 + ln16];
            const float g1 = (float)gb[jrow*32 + 16 + ln16];
            const float gate0 = 1.0f / (1.0f + __expf(-(g0 + bg0)));
            const float gate1 = 1.0f / (1.0f + __expf(-(g1 + bg1)));
            Pww[(quad*4 + r)*44 + ln16]      = (_Float16)(O0[r] * inv * gate0);
            Pww[(quad*4 + r)*44 + 16 + ln16] = (_Float16)(O1[r] * inv * gate1);
        }
        // contiguous 1KB-per-wave store (in-order DS pipe, wave-private)
        {
            const int rr = lane >> 2, cc = lane & 3;
            const halfx4 lo = *(const halfx4*)&Pww[rr*44 + cc*8];
            const halfx4 hi = *(const halfx4*)&Pww[rr*44 + cc*8 + 4];
            halfx8 ov;
            #pragma unroll
            for (int e = 0; e < 4; ++e) { ov[e] = lo[e]; ov[4+e] = hi[e]; }
            *(halfx8*)&ogb[(size_t)(jrow0 + rr)*32 + cc*8] = ov;
        }
    }
}

// ---------------------------------------------------------------------------
// K4: output projection as f16 MFMA GEMM: out[(j*256+i)*128 + c] =
// sum_k og[(i*256+j), k] * woh[c, k] + bo[c], k = h*32+d over 4 head-slices.
// No LDS; A from og fp16 (coalesced), B from woh (L2-resident).
// ---------------------------------------------------------------------------
__global__ __launch_bounds__(256, 4) void outproj_kernel(
    const _Float16* __restrict__ og, const _Float16* __restrict__ woh,
    const float* __restrict__ bo, float* __restrict__ out)
{
    const int t = threadIdx.x, w = t >> 6, lane = t & 63;
    const int ln16 = lane & 15, quad = lane >> 4;
    const int wr = w >> 1, wc = w & 1;
    const int m_base = blockIdx.x * 128 + wr * 64;
    const int n_base = wc * 64;

    floatx4 Cf[4][4];
    const floatx4 z4 = {0.f, 0.f, 0.f, 0.f};
    #pragma unroll
    for (int mt = 0; mt < 4; ++mt)
        #pragma unroll
        for (int nt = 0; nt < 4; ++nt) Cf[mt][nt] = z4;

    #pragma unroll
    for (int ks = 0; ks < 4; ++ks) {   // ks = head
        halfx8 Af[4], Bf[4];
        #pragma unroll
        for (int mt = 0; mt < 4; ++mt)
            Af[mt] = *(const halfx8*)&og[(size_t)ks*2097152 + (size_t)(m_base + mt*16 + ln16)*32 + quad*8];
        #pragma unroll
        for (int nt = 0; nt < 4; ++nt)
            Bf[nt] = *(const halfx8*)&woh[(n_base + nt*16 + ln16)*128 + ks*32 + quad*8];
        #pragma unroll
        for (int mt = 0; mt < 4; ++mt)
            #pragma unroll
            for (int nt = 0; nt < 4; ++nt)
                Cf[mt][nt] = mfma16h(Af[mt], Bf[nt], Cf[mt][nt]);
    }

    float bov[4];
    #pragma unroll
    for (int nt = 0; nt < 4; ++nt) bov[nt] = bo[n_base + nt*16 + ln16];

    #pragma unroll
    for (int mt = 0; mt < 4; ++mt)
        #pragma unroll
        for (int r = 0; r < 4; ++r) {
            const int m = m_base + mt*16 + quad*4 + r;
            const size_t orow = (size_t)(m & 255) * 256 + (m >> 8);  // (j,i)
            #pragma unroll
            for (int nt = 0; nt < 4; ++nt)
                out[orow*128 + n_base + nt*16 + ln16] = Cf[mt][nt][r] + bov[nt];
        }
}

// ---------------------------------------------------------------------------
extern "C" void kernel_launch(void* const* d_in, const int* in_sizes, int n_in,
                              void* d_out, int out_size, void* d_ws, size_t ws_size,
                              hipStream_t stream) {
    const float* x     = (const float*)d_in[0];
    const float* mask  = (const float*)d_in[1];
    const float* lnw   = (const float*)d_in[2];
    const float* lnb   = (const float*)d_in[3];
    const float* wbias = (const float*)d_in[4];
    const float* wq    = (const float*)d_in[5];
    const float* wk    = (const float*)d_in[6];
    const float* wv    = (const float*)d_in[7];
    const float* wg    = (const float*)d_in[8];
    const float* bg    = (const float*)d_in[9];
    const float* wo    = (const float*)d_in[10];
    const float* bo    = (const float*)d_in[11];
    float* out = (float*)d_out;

    char* wsb = (char*)d_ws;
    __bf16*    xn   = (__bf16*)   (wsb);              // 16.78 MB
    float*     tbp  = (float*)    (wsb + 16777216);   //  1.05 MB (permuted)
    __bf16*    wTg  = (__bf16*)   (wsb + 17825792);   //  0.13 MB
    _Float16*  woh  = (_Float16*) (wsb + 17956864);   //  0.03 MB
    __bf16*    qbuf = (__bf16*)   (wsb + 17989632);   // 16.78 MB
    __bf16*    kbuf = (__bf16*)   (wsb + 34766848);   // 16.78 MB
    __bf16*    vbuf = (__bf16*)   (wsb + 51544064);   // 16.78 MB
    __bf16*    gbuf = (__bf16*)   (wsb + 68321280);   // 16.78 MB
    _Float16*  ogh  = (_Float16*) (wsb + 85098496);   // 16.78 MB (total ~102 MB)

    wt_kernel<<<40, 256, 0, stream>>>(wq, wk, wv, wg, wo, wTg, woh);
    ln_kernel<<<16384, 256, 0, stream>>>(x, lnw, lnb, wbias, xn, tbp);
    proj_kernel<<<dim3(512, 4), 256, 0, stream>>>(xn, wTg, qbuf, kbuf, vbuf, gbuf);
    attn_kernel<<<1024, 256, 0, stream>>>(tbp, mask, bg, qbuf, kbuf, vbuf, gbuf, ogh);
    outproj_kernel<<<512, 256, 0, stream>>>(ogh, woh, bo, out);
}

// Round 6
// 302.566 us; speedup vs baseline: 1.1763x; 1.1763x over previous
//
#include <hip/hip_runtime.h>

// Problem constants: B=1, N=256, C=128, H=4, D=32
#define N 256
#define C 128
#define H 4
#define D 32
#define LN_EPS 1e-5f
#define INFB 1e9f
#define SCALE 0.17677669529663687f  // 1/sqrt(32)

typedef __bf16 bf16x8 __attribute__((ext_vector_type(8)));
typedef __bf16 bf16x2 __attribute__((ext_vector_type(2)));
typedef _Float16 halfx8 __attribute__((ext_vector_type(8)));
typedef _Float16 halfx4 __attribute__((ext_vector_type(4)));
typedef float floatx4 __attribute__((ext_vector_type(4)));

__device__ __forceinline__ floatx4 mfma16(bf16x8 a, bf16x8 b, floatx4 c) {
    return __builtin_amdgcn_mfma_f32_16x16x32_bf16(a, b, c, 0, 0, 0);
}
__device__ __forceinline__ floatx4 mfma16h(halfx8 a, halfx8 b, floatx4 c) {
    return __builtin_amdgcn_mfma_f32_16x16x32_f16(a, b, c, 0, 0, 0);
}

// ---------------------------------------------------------------------------
// K0: weight prep. mats 0..3: wTg[mat][n][c] = (bf16) w[c][n] (transposed).
// mat 4: woh[c][k] = (fp16) wo[c][k] (plain convert, layout kept k-major).
// ---------------------------------------------------------------------------
__global__ __launch_bounds__(256) void wt_kernel(
    const float* __restrict__ wq, const float* __restrict__ wk,
    const float* __restrict__ wv, const float* __restrict__ wg,
    const float* __restrict__ wo, __bf16* __restrict__ wTg,
    _Float16* __restrict__ woh)
{
    const int mat = blockIdx.x >> 3, seg = blockIdx.x & 7;
    if (mat == 4) {
        #pragma unroll
        for (int rep = 0; rep < 8; ++rep) {
            const int idx = seg * 2048 + rep * 256 + threadIdx.x;
            woh[idx] = (_Float16)wo[idx];
        }
        return;
    }
    const float* __restrict__ ws_ = (mat == 0) ? wq : (mat == 1) ? wk
                                  : (mat == 2) ? wv : wg;
    #pragma unroll
    for (int rep = 0; rep < 8; ++rep) {
        const int idx = seg * 2048 + rep * 256 + threadIdx.x;
        const int n = idx >> 7, c = idx & 127;
        wTg[mat * 16384 + n * 128 + c] = (__bf16)ws_[c * 128 + n];
    }
}

// ---------------------------------------------------------------------------
// K1: transpose + LayerNorm -> xn bf16, plus tri-bias.
// xn row r = a*256+b holds LN(x[b,a,:]) = x_t[a,b,:].
// Tri-bias is stored PRE-PERMUTED into attn's SWAPPED-QK S-fragment order:
//   value (h, j=a, k=b) is consumed by attn lane = (j&15) + 16*((k&15)>>2)
//   of j-tile (a>>4), at slot kt*4 + r with kt = k>>4, r = k&3. Each attn
//   lane reads its 64 bias values as 16 contiguous float4s.
// ---------------------------------------------------------------------------
__global__ __launch_bounds__(256) void ln_kernel(
    const float* __restrict__ x, const float* __restrict__ lnw,
    const float* __restrict__ lnb, const float* __restrict__ wbias,
    __bf16* __restrict__ xn, float* __restrict__ tbp)
{
    const int t = threadIdx.x;
    const int wv = t >> 6, lane = t & 63;
    const int r = blockIdx.x * 4 + wv;
    const int a = r >> 8, b = r & 255;   // tb value for (h, j=a, k=b)

    const float2 v = *(const float2*)&x[((size_t)b * N + a) * C + lane * 2];
    float s  = v.x + v.y;
    float ss = v.x * v.x + v.y * v.y;
    #pragma unroll
    for (int o = 32; o; o >>= 1) {
        s  += __shfl_xor(s,  o);
        ss += __shfl_xor(ss, o);
    }
    const float mu  = s * (1.0f / 128.0f);
    const float var = ss * (1.0f / 128.0f) - mu * mu;
    const float rs  = rsqrtf(var + LN_EPS);

    const float2 lw = *(const float2*)&lnw[lane * 2];
    const float2 lb = *(const float2*)&lnb[lane * 2];
    const float y0 = (v.x - mu) * rs * lw.x + lb.x;
    const float y1 = (v.y - mu) * rs * lw.y + lb.y;

    bf16x2 xo; xo[0] = (__bf16)y0; xo[1] = (__bf16)y1;
    *(bf16x2*)&xn[(size_t)r * C + lane * 2] = xo;

    // permuted tb address components for (j=a, k=b), swapped-QK layout
    const int jb   = a >> 4;                             // 16-row j-tile
    const int lnA  = (a & 15) | (((b & 15) >> 2) << 4);  // attn lane
    const int slot = ((b >> 4) << 2) | (b & 3);          // kt*4 + r (r=k&3)
    #pragma unroll
    for (int hh = 0; hh < H; ++hh) {
        const float2 wb2 = *(const float2*)&wbias[hh * C + lane * 2];
        float tv = y0 * wb2.x + y1 * wb2.y;
        #pragma unroll
        for (int o = 32; o; o >>= 1) tv += __shfl_xor(tv, o);
        if (lane == 0)
            tbp[(size_t)(((hh * 16 + jb) * 64 + lnA) * 64 + slot)] = tv;
    }
}

// ---------------------------------------------------------------------------
// K2: projection GEMM [65536x128]x[128x128] per mat (Q,K,V,G). 4 waves in
// 2x2 64x64 tiles; C-tiles round-trip wave-private LDS so global writes are
// 4KB-contiguous. Outputs [i*4+h][row][32] bf16; Q pre-scaled.
// ---------------------------------------------------------------------------
__global__ __launch_bounds__(256, 3) void proj_kernel(
    const __bf16* __restrict__ xn, const __bf16* __restrict__ wTg,
    __bf16* __restrict__ qbuf, __bf16* __restrict__ kbuf,
    __bf16* __restrict__ vbuf, __bf16* __restrict__ gbuf)
{
    __shared__ __bf16 Cs[4][64 * 72];

    const int mat = blockIdx.y;
    const int t = threadIdx.x, w = t >> 6, lane = t & 63;
    const int ln16 = lane & 15, quad = lane >> 4;
    const int wr = w >> 1, wc = w & 1;
    const int m_base = blockIdx.x * 128 + wr * 64;
    const int n_base = wc * 64;
    const __bf16* __restrict__ wT = wTg + mat * 16384;

    floatx4 Cf[4][4];
    const floatx4 z4 = {0.f, 0.f, 0.f, 0.f};
    #pragma unroll
    for (int mt = 0; mt < 4; ++mt)
        #pragma unroll
        for (int nt = 0; nt < 4; ++nt) Cf[mt][nt] = z4;

    #pragma unroll
    for (int ks = 0; ks < 4; ++ks) {
        bf16x8 Af[4], Bf[4];
        #pragma unroll
        for (int mt = 0; mt < 4; ++mt)
            Af[mt] = *(const bf16x8*)&xn[(size_t)(m_base + mt*16 + ln16) * 128 + ks*32 + quad*8];
        #pragma unroll
        for (int nt = 0; nt < 4; ++nt)
            Bf[nt] = *(const bf16x8*)&wT[(n_base + nt*16 + ln16) * 128 + ks*32 + quad*8];
        #pragma unroll
        for (int mt = 0; mt < 4; ++mt)
            #pragma unroll
            for (int nt = 0; nt < 4; ++nt)
                Cf[mt][nt] = mfma16(Af[mt], Bf[nt], Cf[mt][nt]);
    }

    const float scl = (mat == 0) ? SCALE : 1.0f;
    __bf16* __restrict__ Cw = &Cs[w][0];
    #pragma unroll
    for (int mt = 0; mt < 4; ++mt)
        #pragma unroll
        for (int nt = 0; nt < 4; ++nt)
            #pragma unroll
            for (int r = 0; r < 4; ++r)
                Cw[(mt*16 + quad*4 + r) * 72 + nt*16 + ln16] =
                    (__bf16)(Cf[mt][nt][r] * scl);

    __bf16* __restrict__ dst = (mat == 0) ? qbuf : (mat == 1) ? kbuf
                             : (mat == 2) ? vbuf : gbuf;
    const int m = m_base + lane;
    const int i = m >> 8, jk = m & 255;
    #pragma unroll
    for (int hf = 0; hf < 2; ++hf) {
        const int hh = wc * 2 + hf;
        __bf16* __restrict__ drow = dst + (((size_t)i*4 + hh)*256 + jk)*32;
        #pragma unroll
        for (int u = 0; u < 4; ++u)
            *(bf16x8*)&drow[u*8] = *(const bf16x8*)&Cw[lane*72 + hf*32 + u*8];
    }
}

// ---------------------------------------------------------------------------
// K3: MFMA attention, one (i,h) per block. SWAPPED QK^T (S = mfma(K,Q)) so
// each lane owns ONE j-row: softmax reduce = 2 shfl_xor; P->PV transpose
// in-register via 4-lane shuffles (no Pw LDS buffer). LDS 44 KB.
// LAUNCH BOUNDS: (256,2) NOT (256,3) — R5 lesson: the min-waves=3 arg cut
// the VGPR budget to 170, the scheduler's load hoisting over the 64-reg
// S[] overflowed it, and everything spilled to scratch (VGPR=84, 156 MB
// scratch writes, 2.4x regression). With budget 256 the allocator can
// still land <=170 and reach 3 blocks/CU via the 44 KB LDS footprint.
// K stays LDS-staged (R3 lesson: direct-global K serializes on L2 latency).
// Rule #20: all S/U indices compile-time constant (scratch disaster R0).
// ---------------------------------------------------------------------------
__global__ __launch_bounds__(256, 2) void attn_kernel(
    const float* __restrict__ tbp, const float* __restrict__ mask,
    const float* __restrict__ bg,
    const __bf16* __restrict__ qbuf, const __bf16* __restrict__ kbuf,
    const __bf16* __restrict__ vbuf, const __bf16* __restrict__ gbuf,
    _Float16* __restrict__ ogh)
{
    const int bid = blockIdx.x;
    const int i = bid & 255, h = bid >> 8;
    const int t = threadIdx.x, w = t >> 6, lane = t & 63;
    const int ln16 = lane & 15, quad = lane >> 4;

    __shared__ __align__(16) __bf16 Ks[256 * 40];      // 20480 B
    __shared__ __align__(16) __bf16 VT[32 * 264];      // 16896 B
    __shared__ __align__(16) _Float16 Pe[4][16 * 44];  //  5632 B
    __shared__ float mb[256];                          //  1024 B
    // total 44032 B -> 3 blocks/CU if VGPR <= 170

    const size_t hb = (size_t)i * 4 + h;
    const __bf16* __restrict__ qb = qbuf + hb * 8192;
    const __bf16* __restrict__ kb = kbuf + hb * 8192;
    const __bf16* __restrict__ vb = vbuf + hb * 8192;
    const __bf16* __restrict__ gb = gbuf + hb * 8192;

    #pragma unroll
    for (int u = 0; u < 4; ++u)
        *(bf16x8*)&Ks[t * 40 + u * 8] = *(const bf16x8*)&kb[t * 32 + u * 8];
    #pragma unroll
    for (int u = 0; u < 4; ++u) {
        const bf16x8 vv = *(const bf16x8*)&vb[t * 32 + u * 8];
        #pragma unroll
        for (int e = 0; e < 8; ++e) VT[(u*8 + e) * 264 + t] = vv[e];
    }
    mb[t] = INFB * (mask[(size_t)t * N + i] - 1.0f);
    __syncthreads();

    const float bg0 = bg[h*32 + ln16], bg1 = bg[h*32 + 16 + ln16];

    _Float16* __restrict__ Pww = &Pe[w][0];
    const floatx4 z4 = {0.f, 0.f, 0.f, 0.f};
    _Float16* __restrict__ ogb = ogh + ((size_t)h * 256 + i) * 8192;

    const int idxA = ln16 + ((quad & 1) << 5);  // source lane for frag words 0,1
    const int idxB = idxA + 16;                 // source lane for frag words 2,3

    #pragma unroll 1
    for (int jt = 0; jt < 4; ++jt) {
        const int jrow0 = w*64 + jt*16;
        // per-lane contiguous 256B slab of pre-permuted tri-bias
        const float* __restrict__ tbl =
            tbp + ((size_t)((h*16 + (w*4 + jt))*64 + lane) << 6);
        const bf16x8 Qf = *(const bf16x8*)&qb[(jrow0 + ln16)*32 + quad*8];

        // ---- swapped scores: S[kt][r] = score(j = jrow0+ln16,
        //      k = kt*16 + quad*4 + r) ----
        floatx4 S[16];
        #pragma unroll
        for (int kt = 0; kt < 16; ++kt) {
            const bf16x8 Kf = *(const bf16x8*)&Ks[(kt*16 + ln16)*40 + quad*8];
            S[kt] = mfma16(Kf, Qf, z4);
        }

        // ---- bias: mask (LDS float4) + tri-bias (global float4) ----
        #pragma unroll
        for (int kt = 0; kt < 16; ++kt) {
            const float4 tb4 = *(const float4*)&tbl[kt*4];
            const float4 mb4 = *(const float4*)&mb[kt*16 + quad*4];
            S[kt][0] += mb4.x + tb4.x;
            S[kt][1] += mb4.y + tb4.y;
            S[kt][2] += mb4.z + tb4.z;
            S[kt][3] += mb4.w + tb4.w;
        }

        // ---- row softmax: lane-local 64-max/sum + 2 shfl_xor ----
        floatx4 a0 = S[0], a1 = S[1], a2 = S[2], a3 = S[3];
        #pragma unroll
        for (int kt = 4; kt < 16; kt += 4) {
            #pragma unroll
            for (int e = 0; e < 4; ++e) {
                a0[e] = fmaxf(a0[e], S[kt+0][e]);
                a1[e] = fmaxf(a1[e], S[kt+1][e]);
                a2[e] = fmaxf(a2[e], S[kt+2][e]);
                a3[e] = fmaxf(a3[e], S[kt+3][e]);
            }
        }
        float mx;
        {
            floatx4 m01, m23;
            #pragma unroll
            for (int e = 0; e < 4; ++e) { m01[e] = fmaxf(a0[e], a1[e]); m23[e] = fmaxf(a2[e], a3[e]); }
            mx = fmaxf(fmaxf(fmaxf(m01[0], m01[1]), fmaxf(m01[2], m01[3])),
                       fmaxf(fmaxf(m23[0], m23[1]), fmaxf(m23[2], m23[3])));
        }
        mx = fmaxf(mx, __shfl_xor(mx, 16));
        mx = fmaxf(mx, __shfl_xor(mx, 32));

        floatx4 lacc = z4;
        #pragma unroll
        for (int kt = 0; kt < 16; ++kt)
            #pragma unroll
            for (int e = 0; e < 4; ++e) {
                const float p = __expf(S[kt][e] - mx);
                S[kt][e] = p; lacc[e] += p;
            }
        float l = (lacc[0] + lacc[1]) + (lacc[2] + lacc[3]);
        l += __shfl_xor(l, 16);
        l += __shfl_xor(l, 32);

        // ---- pack P to bf16 pairs (lane-local) ----
        unsigned int U0[16], U1[16];
        #pragma unroll
        for (int kt = 0; kt < 16; ++kt) {
            bf16x2 p0, p1;
            p0[0] = (__bf16)S[kt][0]; p0[1] = (__bf16)S[kt][1];
            p1[0] = (__bf16)S[kt][2]; p1[1] = (__bf16)S[kt][3];
            U0[kt] = __builtin_bit_cast(unsigned int, p0);
            U1[kt] = __builtin_bit_cast(unsigned int, p1);
        }

        // ---- PV: in-register 4-lane transpose feeds A-frag directly ----
        floatx4 O0 = z4, O1 = z4;
        #pragma unroll
        for (int ks = 0; ks < 8; ++ks) {
            const unsigned int e0a = __shfl(U0[2*ks],   idxA);
            const unsigned int f0a = __shfl(U0[2*ks+1], idxA);
            const unsigned int e1a = __shfl(U1[2*ks],   idxA);
            const unsigned int f1a = __shfl(U1[2*ks+1], idxA);
            const unsigned int e0b = __shfl(U0[2*ks],   idxB);
            const unsigned int f0b = __shfl(U0[2*ks+1], idxB);
            const unsigned int e1b = __shfl(U1[2*ks],   idxB);
            const unsigned int f1b = __shfl(U1[2*ks+1], idxB);
            uint4 pw;
            pw.x = (quad < 2) ? e0a : f0a;
            pw.y = (quad < 2) ? e1a : f1a;
            pw.z = (quad < 2) ? e0b : f0b;
            pw.w = (quad < 2) ? e1b : f1b;
            const bf16x8 PA = __builtin_bit_cast(bf16x8, pw);
            const bf16x8 V0 = *(const bf16x8*)&VT[ln16*264 + ks*32 + quad*8];
            const bf16x8 V1 = *(const bf16x8*)&VT[(16 + ln16)*264 + ks*32 + quad*8];
            O0 = mfma16(PA, V0, O0);
            O1 = mfma16(PA, V1, O1);
        }

        // ---- normalize+gate -> fp16 repack in wave-private LDS ----
        // O0[r]: j = jrow0 + quad*4 + r, d = ln16 (O1: d = 16+ln16).
        // row-sum l lives at lanes keyed by ln16=j&15 -> fetch via shfl.
        const float invl = 1.0f / l;
        #pragma unroll
        for (int r = 0; r < 4; ++r) {
            const float inv = __shfl(invl, quad*4 + r);
            const int jrow = jrow0 + quad*4 + r;
            const float g0 = (float)gb[jrow*32 + ln16];
            const float g1 = (float)gb[jrow*32 + 16 + ln16];
            const float gate0 = 1.0f / (1.0f + __expf(-(g0 + bg0)));
            const float gate1 = 1.0f / (1.0f + __expf(-(g1 + bg1)));
            Pww[(quad*4 + r)*44 + ln16]      = (_Float16)(O0[r] * inv * gate0);
            Pww[(quad*4 + r)*44 + 16 + ln16] = (_Float16)(O1[r] * inv * gate1);
        }
        // contiguous 1KB-per-wave store (in-order DS pipe, wave-private)
        {
            const int rr = lane >> 2, cc = lane & 3;
            const halfx4 lo = *(const halfx4*)&Pww[rr*44 + cc*8];
            const halfx4 hi = *(const halfx4*)&Pww[rr*44 + cc*8 + 4];
            halfx8 ov;
            #pragma unroll
            for (int e = 0; e < 4; ++e) { ov[e] = lo[e]; ov[4+e] = hi[e]; }
            *(halfx8*)&ogb[(size_t)(jrow0 + rr)*32 + cc*8] = ov;
        }
    }
}

// ---------------------------------------------------------------------------
// K4: output projection as f16 MFMA GEMM: out[(j*256+i)*128 + c] =
// sum_k og[(i*256+j), k] * woh[c, k] + bo[c], k = h*32+d over 4 head-slices.
// No LDS; A from og fp16 (coalesced), B from woh (L2-resident).
// ---------------------------------------------------------------------------
__global__ __launch_bounds__(256, 4) void outproj_kernel(
    const _Float16* __restrict__ og, const _Float16* __restrict__ woh,
    const float* __restrict__ bo, float* __restrict__ out)
{
    const int t = threadIdx.x, w = t >> 6, lane = t & 63;
    const int ln16 = lane & 15, quad = lane >> 4;
    const int wr = w >> 1, wc = w & 1;
    const int m_base = blockIdx.x * 128 + wr * 64;
    const int n_base = wc * 64;

    floatx4 Cf[4][4];
    const floatx4 z4 = {0.f, 0.f, 0.f, 0.f};
    #pragma unroll
    for (int mt = 0; mt < 4; ++mt)
        #pragma unroll
        for (int nt = 0; nt < 4; ++nt) Cf[mt][nt] = z4;

    #pragma unroll
    for (int ks = 0; ks < 4; ++ks) {   // ks = head
        halfx8 Af[4], Bf[4];
        #pragma unroll
        for (int mt = 0; mt < 4; ++mt)
            Af[mt] = *(const halfx8*)&og[(size_t)ks*2097152 + (size_t)(m_base + mt*16 + ln16)*32 + quad*8];
        #pragma unroll
        for (int nt = 0; nt < 4; ++nt)
            Bf[nt] = *(const halfx8*)&woh[(n_base + nt*16 + ln16)*128 + ks*32 + quad*8];
        #pragma unroll
        for (int mt = 0; mt < 4; ++mt)
            #pragma unroll
            for (int nt = 0; nt < 4; ++nt)
                Cf[mt][nt] = mfma16h(Af[mt], Bf[nt], Cf[mt][nt]);
    }

    float bov[4];
    #pragma unroll
    for (int nt = 0; nt < 4; ++nt) bov[nt] = bo[n_base + nt*16 + ln16];

    #pragma unroll
    for (int mt = 0; mt < 4; ++mt)
        #pragma unroll
        for (int r = 0; r < 4; ++r) {
            const int m = m_base + mt*16 + quad*4 + r;
            const size_t orow = (size_t)(m & 255) * 256 + (m >> 8);  // (j,i)
            #pragma unroll
            for (int nt = 0; nt < 4; ++nt)
                out[orow*128 + n_base + nt*16 + ln16] = Cf[mt][nt][r] + bov[nt];
        }
}

// ---------------------------------------------------------------------------
extern "C" void kernel_launch(void* const* d_in, const int* in_sizes, int n_in,
                              void* d_out, int out_size, void* d_ws, size_t ws_size,
                              hipStream_t stream) {
    const float* x     = (const float*)d_in[0];
    const float* mask  = (const float*)d_in[1];
    const float* lnw   = (const float*)d_in[2];
    const float* lnb   = (const float*)d_in[3];
    const float* wbias = (const float*)d_in[4];
    const float* wq    = (const float*)d_in[5];
    const float* wk    = (const float*)d_in[6];
    const float* wv    = (const float*)d_in[7];
    const float* wg    = (const float*)d_in[8];
    const float* bg    = (const float*)d_in[9];
    const float* wo    = (const float*)d_in[10];
    const float* bo    = (const float*)d_in[11];
    float* out = (float*)d_out;

    char* wsb = (char*)d_ws;
    __bf16*    xn   = (__bf16*)   (wsb);              // 16.78 MB
    float*     tbp  = (float*)    (wsb + 16777216);   //  1.05 MB (permuted)
    __bf16*    wTg  = (__bf16*)   (wsb + 17825792);   //  0.13 MB
    _Float16*  woh  = (_Float16*) (wsb + 17956864);   //  0.03 MB
    __bf16*    qbuf = (__bf16*)   (wsb + 17989632);   // 16.78 MB
    __bf16*    kbuf = (__bf16*)   (wsb + 34766848);   // 16.78 MB
    __bf16*    vbuf = (__bf16*)   (wsb + 51544064);   // 16.78 MB
    __bf16*    gbuf = (__bf16*)   (wsb + 68321280);   // 16.78 MB
    _Float16*  ogh  = (_Float16*) (wsb + 85098496);   // 16.78 MB (total ~102 MB)

    wt_kernel<<<40, 256, 0, stream>>>(wq, wk, wv, wg, wo, wTg, woh);
    ln_kernel<<<16384, 256, 0, stream>>>(x, lnw, lnb, wbias, xn, tbp);
    proj_kernel<<<dim3(512, 4), 256, 0, stream>>>(xn, wTg, qbuf, kbuf, vbuf, gbuf);
    attn_kernel<<<1024, 256, 0, stream>>>(tbp, mask, bg, qbuf, kbuf, vbuf, gbuf, ogh);
    outproj_kernel<<<512, 256, 0, stream>>>(ogh, woh, bo, out);
}

// Round 7
// 264.030 us; speedup vs baseline: 1.3480x; 1.1460x over previous
//
#include <hip/hip_runtime.h>

// Problem constants: B=1, N=256, C=128, H=4, D=32
#define N 256
#define C 128
#define H 4
#define D 32
#define LN_EPS 1e-5f
#define INFB 1e9f
#define SCALE 0.17677669529663687f  // 1/sqrt(32)

typedef __bf16 bf16x8 __attribute__((ext_vector_type(8)));
typedef __bf16 bf16x2 __attribute__((ext_vector_type(2)));
typedef _Float16 halfx8 __attribute__((ext_vector_type(8)));
typedef _Float16 halfx4 __attribute__((ext_vector_type(4)));
typedef float floatx4 __attribute__((ext_vector_type(4)));

__device__ __forceinline__ floatx4 mfma16(bf16x8 a, bf16x8 b, floatx4 c) {
    return __builtin_amdgcn_mfma_f32_16x16x32_bf16(a, b, c, 0, 0, 0);
}
__device__ __forceinline__ floatx4 mfma16h(halfx8 a, halfx8 b, floatx4 c) {
    return __builtin_amdgcn_mfma_f32_16x16x32_f16(a, b, c, 0, 0, 0);
}

// ---------------------------------------------------------------------------
// K0: weight prep. mats 0..3: wTg[mat][n][c] = (bf16) w[c][n] (transposed).
// mat 4: woh[c][k] = (fp16) wo[c][k] (plain convert, layout kept k-major).
// ---------------------------------------------------------------------------
__global__ __launch_bounds__(256) void wt_kernel(
    const float* __restrict__ wq, const float* __restrict__ wk,
    const float* __restrict__ wv, const float* __restrict__ wg,
    const float* __restrict__ wo, __bf16* __restrict__ wTg,
    _Float16* __restrict__ woh)
{
    const int mat = blockIdx.x >> 3, seg = blockIdx.x & 7;
    if (mat == 4) {
        #pragma unroll
        for (int rep = 0; rep < 8; ++rep) {
            const int idx = seg * 2048 + rep * 256 + threadIdx.x;
            woh[idx] = (_Float16)wo[idx];
        }
        return;
    }
    const float* __restrict__ ws_ = (mat == 0) ? wq : (mat == 1) ? wk
                                  : (mat == 2) ? wv : wg;
    #pragma unroll
    for (int rep = 0; rep < 8; ++rep) {
        const int idx = seg * 2048 + rep * 256 + threadIdx.x;
        const int n = idx >> 7, c = idx & 127;
        wTg[mat * 16384 + n * 128 + c] = (__bf16)ws_[c * 128 + n];
    }
}

// ---------------------------------------------------------------------------
// K1: transpose + LayerNorm -> xn bf16, plus tri-bias.
// xn row r = a*256+b holds LN(x[b,a,:]) = x_t[a,b,:].
// Tri-bias is stored PRE-PERMUTED into attn's SWAPPED-QK S-fragment order:
//   value (h, j=a, k=b) is consumed by attn lane = (j&15) + 16*((k&15)>>2)
//   of j-tile (a>>4), at slot kt*4 + r with kt = k>>4, r = k&3. Each attn
//   lane reads its 64 bias values as 16 contiguous float4s.
// ---------------------------------------------------------------------------
__global__ __launch_bounds__(256) void ln_kernel(
    const float* __restrict__ x, const float* __restrict__ lnw,
    const float* __restrict__ lnb, const float* __restrict__ wbias,
    __bf16* __restrict__ xn, float* __restrict__ tbp)
{
    const int t = threadIdx.x;
    const int wv = t >> 6, lane = t & 63;
    const int r = blockIdx.x * 4 + wv;
    const int a = r >> 8, b = r & 255;   // tb value for (h, j=a, k=b)

    const float2 v = *(const float2*)&x[((size_t)b * N + a) * C + lane * 2];
    float s  = v.x + v.y;
    float ss = v.x * v.x + v.y * v.y;
    #pragma unroll
    for (int o = 32; o; o >>= 1) {
        s  += __shfl_xor(s,  o);
        ss += __shfl_xor(ss, o);
    }
    const float mu  = s * (1.0f / 128.0f);
    const float var = ss * (1.0f / 128.0f) - mu * mu;
    const float rs  = rsqrtf(var + LN_EPS);

    const float2 lw = *(const float2*)&lnw[lane * 2];
    const float2 lb = *(const float2*)&lnb[lane * 2];
    const float y0 = (v.x - mu) * rs * lw.x + lb.x;
    const float y1 = (v.y - mu) * rs * lw.y + lb.y;

    bf16x2 xo; xo[0] = (__bf16)y0; xo[1] = (__bf16)y1;
    *(bf16x2*)&xn[(size_t)r * C + lane * 2] = xo;

    // permuted tb address components for (j=a, k=b), swapped-QK layout
    const int jb   = a >> 4;                             // 16-row j-tile
    const int lnA  = (a & 15) | (((b & 15) >> 2) << 4);  // attn lane
    const int slot = ((b >> 4) << 2) | (b & 3);          // kt*4 + r (r=k&3)
    #pragma unroll
    for (int hh = 0; hh < H; ++hh) {
        const float2 wb2 = *(const float2*)&wbias[hh * C + lane * 2];
        float tv = y0 * wb2.x + y1 * wb2.y;
        #pragma unroll
        for (int o = 32; o; o >>= 1) tv += __shfl_xor(tv, o);
        if (lane == 0)
            tbp[(size_t)(((hh * 16 + jb) * 64 + lnA) * 64 + slot)] = tv;
    }
}

// ---------------------------------------------------------------------------
// K2: projection GEMM [65536x128]x[128x128] per mat (Q,K,V,G). 4 waves in
// 2x2 64x64 tiles; C-tiles round-trip wave-private LDS so global writes are
// 4KB-contiguous. Outputs [i*4+h][row][32] bf16; Q pre-scaled.
// ---------------------------------------------------------------------------
__global__ __launch_bounds__(256, 3) void proj_kernel(
    const __bf16* __restrict__ xn, const __bf16* __restrict__ wTg,
    __bf16* __restrict__ qbuf, __bf16* __restrict__ kbuf,
    __bf16* __restrict__ vbuf, __bf16* __restrict__ gbuf)
{
    __shared__ __bf16 Cs[4][64 * 72];

    const int mat = blockIdx.y;
    const int t = threadIdx.x, w = t >> 6, lane = t & 63;
    const int ln16 = lane & 15, quad = lane >> 4;
    const int wr = w >> 1, wc = w & 1;
    const int m_base = blockIdx.x * 128 + wr * 64;
    const int n_base = wc * 64;
    const __bf16* __restrict__ wT = wTg + mat * 16384;

    floatx4 Cf[4][4];
    const floatx4 z4 = {0.f, 0.f, 0.f, 0.f};
    #pragma unroll
    for (int mt = 0; mt < 4; ++mt)
        #pragma unroll
        for (int nt = 0; nt < 4; ++nt) Cf[mt][nt] = z4;

    #pragma unroll
    for (int ks = 0; ks < 4; ++ks) {
        bf16x8 Af[4], Bf[4];
        #pragma unroll
        for (int mt = 0; mt < 4; ++mt)
            Af[mt] = *(const bf16x8*)&xn[(size_t)(m_base + mt*16 + ln16) * 128 + ks*32 + quad*8];
        #pragma unroll
        for (int nt = 0; nt < 4; ++nt)
            Bf[nt] = *(const bf16x8*)&wT[(n_base + nt*16 + ln16) * 128 + ks*32 + quad*8];
        #pragma unroll
        for (int mt = 0; mt < 4; ++mt)
            #pragma unroll
            for (int nt = 0; nt < 4; ++nt)
                Cf[mt][nt] = mfma16(Af[mt], Bf[nt], Cf[mt][nt]);
    }

    const float scl = (mat == 0) ? SCALE : 1.0f;
    __bf16* __restrict__ Cw = &Cs[w][0];
    #pragma unroll
    for (int mt = 0; mt < 4; ++mt)
        #pragma unroll
        for (int nt = 0; nt < 4; ++nt)
            #pragma unroll
            for (int r = 0; r < 4; ++r)
                Cw[(mt*16 + quad*4 + r) * 72 + nt*16 + ln16] =
                    (__bf16)(Cf[mt][nt][r] * scl);

    __bf16* __restrict__ dst = (mat == 0) ? qbuf : (mat == 1) ? kbuf
                             : (mat == 2) ? vbuf : gbuf;
    const int m = m_base + lane;
    const int i = m >> 8, jk = m & 255;
    #pragma unroll
    for (int hf = 0; hf < 2; ++hf) {
        const int hh = wc * 2 + hf;
        __bf16* __restrict__ drow = dst + (((size_t)i*4 + hh)*256 + jk)*32;
        #pragma unroll
        for (int u = 0; u < 4; ++u)
            *(bf16x8*)&drow[u*8] = *(const bf16x8*)&Cw[lane*72 + hf*32 + u*8];
    }
}

// ---------------------------------------------------------------------------
// K3: MFMA attention, one (i,h) per block. SWAPPED QK^T (S = mfma(K,Q)),
// each lane owns ONE j-row; softmax reduce = 2 shfl_xor; P->PV transpose
// in-register via 4-lane shuffles (no Pw LDS buffer). LDS 44 KB.
// REGISTER-PRESSURE DISCIPLINE (R6 lesson): the bias must be folded into
// the MFMA C-operand — a separate bias phase lets the scheduler hoist 16
// float4 loads (64 VGPRs) on top of the fully-live S[16] (64 VGPRs),
// blowing the 128 tier and spilling ~50 MB to scratch. Each tb4 now dies
// into its own MFMA. exp+sum+bf16pack are fused so S dies as U is born.
// K stays LDS-staged (R3: direct-global K serializes on L2 latency).
// Launch bounds (256,2) — (256,3) caps the budget at 170 and the allocator
// gives up entirely (R5: VGPR=84, everything in scratch).
// ---------------------------------------------------------------------------
__global__ __launch_bounds__(256, 2) void attn_kernel(
    const float* __restrict__ tbp, const float* __restrict__ mask,
    const float* __restrict__ bg,
    const __bf16* __restrict__ qbuf, const __bf16* __restrict__ kbuf,
    const __bf16* __restrict__ vbuf, const __bf16* __restrict__ gbuf,
    _Float16* __restrict__ ogh)
{
    const int bid = blockIdx.x;
    const int i = bid & 255, h = bid >> 8;
    const int t = threadIdx.x, w = t >> 6, lane = t & 63;
    const int ln16 = lane & 15, quad = lane >> 4;

    __shared__ __align__(16) __bf16 Ks[256 * 40];      // 20480 B
    __shared__ __align__(16) __bf16 VT[32 * 264];      // 16896 B
    __shared__ __align__(16) _Float16 Pe[4][16 * 44];  //  5632 B
    __shared__ float mb[256];                          //  1024 B
    // total 44032 B -> 3 blocks/CU if VGPR <= 170

    const size_t hb = (size_t)i * 4 + h;
    const __bf16* __restrict__ qb = qbuf + hb * 8192;
    const __bf16* __restrict__ kb = kbuf + hb * 8192;
    const __bf16* __restrict__ vb = vbuf + hb * 8192;
    const __bf16* __restrict__ gb = gbuf + hb * 8192;

    #pragma unroll
    for (int u = 0; u < 4; ++u)
        *(bf16x8*)&Ks[t * 40 + u * 8] = *(const bf16x8*)&kb[t * 32 + u * 8];
    #pragma unroll
    for (int u = 0; u < 4; ++u) {
        const bf16x8 vv = *(const bf16x8*)&vb[t * 32 + u * 8];
        #pragma unroll
        for (int e = 0; e < 8; ++e) VT[(u*8 + e) * 264 + t] = vv[e];
    }
    mb[t] = INFB * (mask[(size_t)t * N + i] - 1.0f);
    __syncthreads();

    const float bg0 = bg[h*32 + ln16], bg1 = bg[h*32 + 16 + ln16];

    _Float16* __restrict__ Pww = &Pe[w][0];
    const floatx4 z4 = {0.f, 0.f, 0.f, 0.f};
    _Float16* __restrict__ ogb = ogh + ((size_t)h * 256 + i) * 8192;

    const int idxA = ln16 + ((quad & 1) << 5);  // source lane for frag words 0,1
    const int idxB = idxA + 16;                 // source lane for frag words 2,3

    #pragma unroll 1
    for (int jt = 0; jt < 4; ++jt) {
        const int jrow0 = w*64 + jt*16;
        // per-lane contiguous 256B slab of pre-permuted tri-bias
        const float* __restrict__ tbl =
            tbp + ((size_t)((h*16 + (w*4 + jt))*64 + lane) << 6);
        const bf16x8 Qf = *(const bf16x8*)&qb[(jrow0 + ln16)*32 + quad*8];

        // ---- scores with bias folded into MFMA C-operand:
        //      S[kt][r] = score(j=jrow0+ln16, k=kt*16+quad*4+r) + mask + tri ----
        floatx4 S[16];
        #pragma unroll
        for (int kt = 0; kt < 16; ++kt) {
            const float4 tb4 = *(const float4*)&tbl[kt*4];
            const float4 mb4 = *(const float4*)&mb[kt*16 + quad*4];
            floatx4 c;
            c[0] = mb4.x + tb4.x;
            c[1] = mb4.y + tb4.y;
            c[2] = mb4.z + tb4.z;
            c[3] = mb4.w + tb4.w;
            const bf16x8 Kf = *(const bf16x8*)&Ks[(kt*16 + ln16)*40 + quad*8];
            S[kt] = mfma16(Kf, Qf, c);
        }

        // ---- row max: 4 parallel per-element chains + 2 shfl_xor ----
        float m0 = S[0][0], m1 = S[0][1], m2 = S[0][2], m3 = S[0][3];
        #pragma unroll
        for (int kt = 1; kt < 16; ++kt) {
            m0 = fmaxf(m0, S[kt][0]);
            m1 = fmaxf(m1, S[kt][1]);
            m2 = fmaxf(m2, S[kt][2]);
            m3 = fmaxf(m3, S[kt][3]);
        }
        float mx = fmaxf(fmaxf(m0, m1), fmaxf(m2, m3));
        mx = fmaxf(mx, __shfl_xor(mx, 16));
        mx = fmaxf(mx, __shfl_xor(mx, 32));

        // ---- fused exp + sum + bf16 pack (S dies as U is born) ----
        unsigned int U0[16], U1[16];
        float l0 = 0.f, l1 = 0.f, l2 = 0.f, l3 = 0.f;
        #pragma unroll
        for (int kt = 0; kt < 16; ++kt) {
            const float p0 = __expf(S[kt][0] - mx);
            const float p1 = __expf(S[kt][1] - mx);
            const float p2 = __expf(S[kt][2] - mx);
            const float p3 = __expf(S[kt][3] - mx);
            l0 += p0; l1 += p1; l2 += p2; l3 += p3;
            bf16x2 q0, q1;
            q0[0] = (__bf16)p0; q0[1] = (__bf16)p1;
            q1[0] = (__bf16)p2; q1[1] = (__bf16)p3;
            U0[kt] = __builtin_bit_cast(unsigned int, q0);
            U1[kt] = __builtin_bit_cast(unsigned int, q1);
        }
        float l = (l0 + l1) + (l2 + l3);
        l += __shfl_xor(l, 16);
        l += __shfl_xor(l, 32);

        // ---- PV: in-register 4-lane transpose feeds A-frag directly ----
        floatx4 O0 = z4, O1 = z4;
        #pragma unroll
        for (int ks = 0; ks < 8; ++ks) {
            const unsigned int e0a = __shfl(U0[2*ks],   idxA);
            const unsigned int f0a = __shfl(U0[2*ks+1], idxA);
            const unsigned int e1a = __shfl(U1[2*ks],   idxA);
            const unsigned int f1a = __shfl(U1[2*ks+1], idxA);
            const unsigned int e0b = __shfl(U0[2*ks],   idxB);
            const unsigned int f0b = __shfl(U0[2*ks+1], idxB);
            const unsigned int e1b = __shfl(U1[2*ks],   idxB);
            const unsigned int f1b = __shfl(U1[2*ks+1], idxB);
            uint4 pw;
            pw.x = (quad < 2) ? e0a : f0a;
            pw.y = (quad < 2) ? e1a : f1a;
            pw.z = (quad < 2) ? e0b : f0b;
            pw.w = (quad < 2) ? e1b : f1b;
            const bf16x8 PA = __builtin_bit_cast(bf16x8, pw);
            const bf16x8 V0 = *(const bf16x8*)&VT[ln16*264 + ks*32 + quad*8];
            const bf16x8 V1 = *(const bf16x8*)&VT[(16 + ln16)*264 + ks*32 + quad*8];
            O0 = mfma16(PA, V0, O0);
            O1 = mfma16(PA, V1, O1);
        }

        // ---- normalize+gate -> fp16 repack in wave-private LDS ----
        // O0[r]: j = jrow0 + quad*4 + r, d = ln16 (O1: d = 16+ln16).
        // row-sum l lives at lanes keyed by ln16=j&15 -> fetch via shfl.
        const float invl = 1.0f / l;
        #pragma unroll
        for (int r = 0; r < 4; ++r) {
            const float inv = __shfl(invl, quad*4 + r);
            const int jrow = jrow0 + quad*4 + r;
            const float g0 = (float)gb[jrow*32 + ln16];
            const float g1 = (float)gb[jrow*32 + 16 + ln16];
            const float gate0 = 1.0f / (1.0f + __expf(-(g0 + bg0)));
            const float gate1 = 1.0f / (1.0f + __expf(-(g1 + bg1)));
            Pww[(quad*4 + r)*44 + ln16]      = (_Float16)(O0[r] * inv * gate0);
            Pww[(quad*4 + r)*44 + 16 + ln16] = (_Float16)(O1[r] * inv * gate1);
        }
        // contiguous 1KB-per-wave store (in-order DS pipe, wave-private)
        {
            const int rr = lane >> 2, cc = lane & 3;
            const halfx4 lo = *(const halfx4*)&Pww[rr*44 + cc*8];
            const halfx4 hi = *(const halfx4*)&Pww[rr*44 + cc*8 + 4];
            halfx8 ov;
            #pragma unroll
            for (int e = 0; e < 4; ++e) { ov[e] = lo[e]; ov[4+e] = hi[e]; }
            *(halfx8*)&ogb[(size_t)(jrow0 + rr)*32 + cc*8] = ov;
        }
    }
}

// ---------------------------------------------------------------------------
// K4: output projection as f16 MFMA GEMM: out[(j*256+i)*128 + c] =
// sum_k og[(i*256+j), k] * woh[c, k] + bo[c], k = h*32+d over 4 head-slices.
// No LDS; A from og fp16 (coalesced), B from woh (L2-resident).
// ---------------------------------------------------------------------------
__global__ __launch_bounds__(256, 4) void outproj_kernel(
    const _Float16* __restrict__ og, const _Float16* __restrict__ woh,
    const float* __restrict__ bo, float* __restrict__ out)
{
    const int t = threadIdx.x, w = t >> 6, lane = t & 63;
    const int ln16 = lane & 15, quad = lane >> 4;
    const int wr = w >> 1, wc = w & 1;
    const int m_base = blockIdx.x * 128 + wr * 64;
    const int n_base = wc * 64;

    floatx4 Cf[4][4];
    const floatx4 z4 = {0.f, 0.f, 0.f, 0.f};
    #pragma unroll
    for (int mt = 0; mt < 4; ++mt)
        #pragma unroll
        for (int nt = 0; nt < 4; ++nt) Cf[mt][nt] = z4;

    #pragma unroll
    for (int ks = 0; ks < 4; ++ks) {   // ks = head
        halfx8 Af[4], Bf[4];
        #pragma unroll
        for (int mt = 0; mt < 4; ++mt)
            Af[mt] = *(const halfx8*)&og[(size_t)ks*2097152 + (size_t)(m_base + mt*16 + ln16)*32 + quad*8];
        #pragma unroll
        for (int nt = 0; nt < 4; ++nt)
            Bf[nt] = *(const halfx8*)&woh[(n_base + nt*16 + ln16)*128 + ks*32 + quad*8];
        #pragma unroll
        for (int mt = 0; mt < 4; ++mt)
            #pragma unroll
            for (int nt = 0; nt < 4; ++nt)
                Cf[mt][nt] = mfma16h(Af[mt], Bf[nt], Cf[mt][nt]);
    }

    float bov[4];
    #pragma unroll
    for (int nt = 0; nt < 4; ++nt) bov[nt] = bo[n_base + nt*16 + ln16];

    #pragma unroll
    for (int mt = 0; mt < 4; ++mt)
        #pragma unroll
        for (int r = 0; r < 4; ++r) {
            const int m = m_base + mt*16 + quad*4 + r;
            const size_t orow = (size_t)(m & 255) * 256 + (m >> 8);  // (j,i)
            #pragma unroll
            for (int nt = 0; nt < 4; ++nt)
                out[orow*128 + n_base + nt*16 + ln16] = Cf[mt][nt][r] + bov[nt];
        }
}

// ---------------------------------------------------------------------------
extern "C" void kernel_launch(void* const* d_in, const int* in_sizes, int n_in,
                              void* d_out, int out_size, void* d_ws, size_t ws_size,
                              hipStream_t stream) {
    const float* x     = (const float*)d_in[0];
    const float* mask  = (const float*)d_in[1];
    const float* lnw   = (const float*)d_in[2];
    const float* lnb   = (const float*)d_in[3];
    const float* wbias = (const float*)d_in[4];
    const float* wq    = (const float*)d_in[5];
    const float* wk    = (const float*)d_in[6];
    const float* wv    = (const float*)d_in[7];
    const float* wg    = (const float*)d_in[8];
    const float* bg    = (const float*)d_in[9];
    const float* wo    = (const float*)d_in[10];
    const float* bo    = (const float*)d_in[11];
    float* out = (float*)d_out;

    char* wsb = (char*)d_ws;
    __bf16*    xn   = (__bf16*)   (wsb);              // 16.78 MB
    float*     tbp  = (float*)    (wsb + 16777216);   //  1.05 MB (permuted)
    __bf16*    wTg  = (__bf16*)   (wsb + 17825792);   //  0.13 MB
    _Float16*  woh  = (_Float16*) (wsb + 17956864);   //  0.03 MB
    __bf16*    qbuf = (__bf16*)   (wsb + 17989632);   // 16.78 MB
    __bf16*    kbuf = (__bf16*)   (wsb + 34766848);   // 16.78 MB
    __bf16*    vbuf = (__bf16*)   (wsb + 51544064);   // 16.78 MB
    __bf16*    gbuf = (__bf16*)   (wsb + 68321280);   // 16.78 MB
    _Float16*  ogh  = (_Float16*) (wsb + 85098496);   // 16.78 MB (total ~102 MB)

    wt_kernel<<<40, 256, 0, stream>>>(wq, wk, wv, wg, wo, wTg, woh);
    ln_kernel<<<16384, 256, 0, stream>>>(x, lnw, lnb, wbias, xn, tbp);
    proj_kernel<<<dim3(512, 4), 256, 0, stream>>>(xn, wTg, qbuf, kbuf, vbuf, gbuf);
    attn_kernel<<<1024, 256, 0, stream>>>(tbp, mask, bg, qbuf, kbuf, vbuf, gbuf, ogh);
    outproj_kernel<<<512, 256, 0, stream>>>(ogh, woh, bo, out);
}

// Round 8
// 231.400 us; speedup vs baseline: 1.5381x; 1.1410x over previous
//
#include <hip/hip_runtime.h>

// Problem constants: B=1, N=256, C=128, H=4, D=32
#define N 256
#define C 128
#define H 4
#define D 32
#define LN_EPS 1e-5f
#define INFB 1e9f
#define SCALE 0.17677669529663687f  // 1/sqrt(32)

typedef __bf16 bf16x8 __attribute__((ext_vector_type(8)));
typedef __bf16 bf16x4 __attribute__((ext_vector_type(4)));
typedef __bf16 bf16x2 __attribute__((ext_vector_type(2)));
typedef _Float16 halfx8 __attribute__((ext_vector_type(8)));
typedef float floatx4 __attribute__((ext_vector_type(4)));

__device__ __forceinline__ floatx4 mfma16(bf16x8 a, bf16x8 b, floatx4 c) {
    return __builtin_amdgcn_mfma_f32_16x16x32_bf16(a, b, c, 0, 0, 0);
}
__device__ __forceinline__ floatx4 mfma16h(halfx8 a, halfx8 b, floatx4 c) {
    return __builtin_amdgcn_mfma_f32_16x16x32_f16(a, b, c, 0, 0, 0);
}

// ---------------------------------------------------------------------------
// K0: weight prep. mats 0..3: wTg[mat][n][c] = (bf16) w[c][n] (transposed).
// mat 4: woh[c][k] = (fp16) wo[c][k] (plain convert, layout kept k-major).
// ---------------------------------------------------------------------------
__global__ __launch_bounds__(256) void wt_kernel(
    const float* __restrict__ wq, const float* __restrict__ wk,
    const float* __restrict__ wv, const float* __restrict__ wg,
    const float* __restrict__ wo, __bf16* __restrict__ wTg,
    _Float16* __restrict__ woh)
{
    const int mat = blockIdx.x >> 3, seg = blockIdx.x & 7;
    if (mat == 4) {
        #pragma unroll
        for (int rep = 0; rep < 8; ++rep) {
            const int idx = seg * 2048 + rep * 256 + threadIdx.x;
            woh[idx] = (_Float16)wo[idx];
        }
        return;
    }
    const float* __restrict__ ws_ = (mat == 0) ? wq : (mat == 1) ? wk
                                  : (mat == 2) ? wv : wg;
    #pragma unroll
    for (int rep = 0; rep < 8; ++rep) {
        const int idx = seg * 2048 + rep * 256 + threadIdx.x;
        const int n = idx >> 7, c = idx & 127;
        wTg[mat * 16384 + n * 128 + c] = (__bf16)ws_[c * 128 + n];
    }
}

// ---------------------------------------------------------------------------
// K1: transpose + LayerNorm -> xn bf16, plus tri-bias (PRE-PERMUTED tbp).
// 32 LANES PER ROW (was 64): float4 loads (16B/lane), shfl depth 5 (was 6),
// 2 rows/wave, grid halved to 8192 — ln was ~36 serialized DS-pipe shfl
// ops per row x 65536 rows; this cuts DS ops/row ~40% and doubles rows in
// flight. Row r = a*256+b holds LN(x[b,a,:]); tbp layout UNCHANGED
// (HW-validated in R4): value (h,j=a,k=b) -> tbp[((h*16+jb)*64+lnA)*64+slot],
// jb=a>>4, lnA=(b&15)|(((a&15)>>2)<<4), slot=((b>>4)<<2)|(a&3).
// ---------------------------------------------------------------------------
__global__ __launch_bounds__(256) void ln_kernel(
    const float* __restrict__ x, const float* __restrict__ lnw,
    const float* __restrict__ lnb, const float* __restrict__ wbias,
    __bf16* __restrict__ xn, float* __restrict__ tbp)
{
    const int t = threadIdx.x;
    const int wv = t >> 6, half = (t >> 5) & 1, lane = t & 31;
    const int r = blockIdx.x * 8 + wv * 2 + half;
    const int a = r >> 8, b = r & 255;   // tb value for (h, j=a, k=b)

    const float4 v = *(const float4*)&x[((size_t)b * N + a) * C + lane * 4];
    float s  = v.x + v.y + v.z + v.w;
    float ss = v.x*v.x + v.y*v.y + v.z*v.z + v.w*v.w;
    #pragma unroll
    for (int o = 16; o; o >>= 1) {
        s  += __shfl_xor(s,  o);
        ss += __shfl_xor(ss, o);
    }
    const float mu  = s * (1.0f / 128.0f);
    const float var = ss * (1.0f / 128.0f) - mu * mu;
    const float rs  = rsqrtf(var + LN_EPS);

    const float4 lw = *(const float4*)&lnw[lane * 4];
    const float4 lb = *(const float4*)&lnb[lane * 4];
    const float y0 = (v.x - mu) * rs * lw.x + lb.x;
    const float y1 = (v.y - mu) * rs * lw.y + lb.y;
    const float y2 = (v.z - mu) * rs * lw.z + lb.z;
    const float y3 = (v.w - mu) * rs * lw.w + lb.w;

    bf16x4 xo;
    xo[0] = (__bf16)y0; xo[1] = (__bf16)y1;
    xo[2] = (__bf16)y2; xo[3] = (__bf16)y3;
    *(bf16x4*)&xn[(size_t)r * C + lane * 4] = xo;

    // permuted tb address components for (j=a, k=b)
    const int jb   = a >> 4;                             // 16-row j-tile
    const int lnA  = (b & 15) | (((a & 15) >> 2) << 4);  // attn lane
    const int slot = ((b >> 4) << 2) | (a & 3);          // kt*4 + r
    #pragma unroll
    for (int hh = 0; hh < H; ++hh) {
        const float4 wb4 = *(const float4*)&wbias[hh * C + lane * 4];
        float tv = y0 * wb4.x + y1 * wb4.y + y2 * wb4.z + y3 * wb4.w;
        #pragma unroll
        for (int o = 16; o; o >>= 1) tv += __shfl_xor(tv, o);
        if (lane == 0)
            tbp[(size_t)(((hh * 16 + jb) * 64 + lnA) * 64 + slot)] = tv;
    }
}

// ---------------------------------------------------------------------------
// K2: projection GEMM [65536x128]x[128x128] per mat (Q,K,V,G). 4 waves in
// 2x2 64x64 tiles; C-tiles round-trip wave-private LDS so global writes are
// 4KB-contiguous. Outputs [i*4+h][row][32] bf16; Q pre-scaled.
// ---------------------------------------------------------------------------
__global__ __launch_bounds__(256, 3) void proj_kernel(
    const __bf16* __restrict__ xn, const __bf16* __restrict__ wTg,
    __bf16* __restrict__ qbuf, __bf16* __restrict__ kbuf,
    __bf16* __restrict__ vbuf, __bf16* __restrict__ gbuf)
{
    __shared__ __bf16 Cs[4][64 * 72];

    const int mat = blockIdx.y;
    const int t = threadIdx.x, w = t >> 6, lane = t & 63;
    const int ln16 = lane & 15, quad = lane >> 4;
    const int wr = w >> 1, wc = w & 1;
    const int m_base = blockIdx.x * 128 + wr * 64;
    const int n_base = wc * 64;
    const __bf16* __restrict__ wT = wTg + mat * 16384;

    floatx4 Cf[4][4];
    const floatx4 z4 = {0.f, 0.f, 0.f, 0.f};
    #pragma unroll
    for (int mt = 0; mt < 4; ++mt)
        #pragma unroll
        for (int nt = 0; nt < 4; ++nt) Cf[mt][nt] = z4;

    #pragma unroll
    for (int ks = 0; ks < 4; ++ks) {
        bf16x8 Af[4], Bf[4];
        #pragma unroll
        for (int mt = 0; mt < 4; ++mt)
            Af[mt] = *(const bf16x8*)&xn[(size_t)(m_base + mt*16 + ln16) * 128 + ks*32 + quad*8];
        #pragma unroll
        for (int nt = 0; nt < 4; ++nt)
            Bf[nt] = *(const bf16x8*)&wT[(n_base + nt*16 + ln16) * 128 + ks*32 + quad*8];
        #pragma unroll
        for (int mt = 0; mt < 4; ++mt)
            #pragma unroll
            for (int nt = 0; nt < 4; ++nt)
                Cf[mt][nt] = mfma16(Af[mt], Bf[nt], Cf[mt][nt]);
    }

    const float scl = (mat == 0) ? SCALE : 1.0f;
    __bf16* __restrict__ Cw = &Cs[w][0];
    #pragma unroll
    for (int mt = 0; mt < 4; ++mt)
        #pragma unroll
        for (int nt = 0; nt < 4; ++nt)
            #pragma unroll
            for (int r = 0; r < 4; ++r)
                Cw[(mt*16 + quad*4 + r) * 72 + nt*16 + ln16] =
                    (__bf16)(Cf[mt][nt][r] * scl);

    __bf16* __restrict__ dst = (mat == 0) ? qbuf : (mat == 1) ? kbuf
                             : (mat == 2) ? vbuf : gbuf;
    const int m = m_base + lane;
    const int i = m >> 8, jk = m & 255;
    #pragma unroll
    for (int hf = 0; hf < 2; ++hf) {
        const int hh = wc * 2 + hf;
        __bf16* __restrict__ drow = dst + (((size_t)i*4 + hh)*256 + jk)*32;
        #pragma unroll
        for (int u = 0; u < 4; ++u)
            *(bf16x8*)&drow[u*8] = *(const bf16x8*)&Cw[lane*72 + hf*32 + u*8];
    }
}

// ---------------------------------------------------------------------------
// K3: MFMA attention, one (i,h) per block — PROVEN R4 STRUCTURE (72 us):
// K staged to LDS (pad-40), V transposed to LDS (stride 264), full-row
// softmax in C-frags, P->LDS->PV, fp16 repack epilogue. The swapped-QK +
// register-transpose rewrite (R5-R7) never beat this (84 us best).
// ONE change vs R4: bias (mask + pre-permuted tri) folded into the MFMA
// C-operand — each tb4 float4 dies into its own MFMA, so the scheduler
// cannot pile 16 hoisted loads on top of the live S[16] (R6 spill lesson),
// and the 64 VALU adds/lane/jt disappear.
// Rule #20: all S[] indices compile-time constant.
// Launch bounds (256,2): min-waves=3 caps VGPR at 170 and the allocator
// spills everything (R5: VGPR=84, 156 MB scratch).
// ---------------------------------------------------------------------------
__global__ __launch_bounds__(256, 2) void attn_kernel(
    const float* __restrict__ tbp, const float* __restrict__ mask,
    const float* __restrict__ bg,
    const __bf16* __restrict__ qbuf, const __bf16* __restrict__ kbuf,
    const __bf16* __restrict__ vbuf, const __bf16* __restrict__ gbuf,
    _Float16* __restrict__ ogh)
{
    const int bid = blockIdx.x;
    const int i = bid & 255, h = bid >> 8;
    const int t = threadIdx.x, w = t >> 6, lane = t & 63;
    const int ln16 = lane & 15, quad = lane >> 4;

    __shared__ __align__(16) __bf16 Ks[256 * 40];      // 20480 B
    __shared__ __align__(16) __bf16 VT[32 * 264];      // 16896 B
    __shared__ __align__(16) __bf16 Pw[4][16 * 264];   // 33792 B
    __shared__ float mb[256];                          //  1024 B

    const size_t hb = (size_t)i * 4 + h;
    const __bf16* __restrict__ qb = qbuf + hb * 8192;
    const __bf16* __restrict__ kb = kbuf + hb * 8192;
    const __bf16* __restrict__ vb = vbuf + hb * 8192;
    const __bf16* __restrict__ gb = gbuf + hb * 8192;

    #pragma unroll
    for (int u = 0; u < 4; ++u)
        *(bf16x8*)&Ks[t * 40 + u * 8] = *(const bf16x8*)&kb[t * 32 + u * 8];
    #pragma unroll
    for (int u = 0; u < 4; ++u) {
        const bf16x8 vv = *(const bf16x8*)&vb[t * 32 + u * 8];
        #pragma unroll
        for (int e = 0; e < 8; ++e) VT[(u*8 + e) * 264 + t] = vv[e];
    }
    mb[t] = INFB * (mask[(size_t)t * N + i] - 1.0f);
    __syncthreads();

    const float bg0 = bg[h*32 + ln16], bg1 = bg[h*32 + 16 + ln16];

    float mbv[16];
    #pragma unroll
    for (int kt = 0; kt < 16; ++kt) mbv[kt] = mb[kt*16 + ln16];

    __bf16* __restrict__ Pww = &Pw[w][0];
    const floatx4 z4 = {0.f, 0.f, 0.f, 0.f};
    _Float16* __restrict__ ogb = ogh + ((size_t)h * 256 + i) * 8192;

    #pragma unroll 1
    for (int jt = 0; jt < 4; ++jt) {
        const int jrow0 = w*64 + jt*16;
        // per-lane contiguous 256B slab of pre-permuted tri-bias
        const float* __restrict__ tbl =
            tbp + ((size_t)((h*16 + (w*4 + jt))*64 + lane) << 6);
        const bf16x8 Qf = *(const bf16x8*)&qb[(jrow0 + ln16)*32 + quad*8];

        // ---- scores with bias folded into the MFMA C-operand ----
        floatx4 S[16];
        #pragma unroll
        for (int kt = 0; kt < 16; ++kt) {
            const float4 tb4 = *(const float4*)&tbl[kt*4];
            const float mbk = mbv[kt];
            floatx4 c;
            c[0] = mbk + tb4.x;
            c[1] = mbk + tb4.y;
            c[2] = mbk + tb4.z;
            c[3] = mbk + tb4.w;
            const bf16x8 Kf = *(const bf16x8*)&Ks[(kt*16 + ln16)*40 + quad*8];
            S[kt] = mfma16(Qf, Kf, c);
        }

        // ---- full-row softmax (16-lane shfl reduce) ----
        float mrow[4], l[4];
        #pragma unroll
        for (int r = 0; r < 4; ++r) {
            float mx = S[0][r];
            #pragma unroll
            for (int kt = 1; kt < 16; ++kt) mx = fmaxf(mx, S[kt][r]);
            #pragma unroll
            for (int off = 1; off < 16; off <<= 1) mx = fmaxf(mx, __shfl_xor(mx, off));
            mrow[r] = mx; l[r] = 0.f;
        }
        #pragma unroll
        for (int kt = 0; kt < 16; ++kt)
            #pragma unroll
            for (int r = 0; r < 4; ++r) {
                const float p = __expf(S[kt][r] - mrow[r]);
                S[kt][r] = p; l[r] += p;
            }
        #pragma unroll
        for (int r = 0; r < 4; ++r)
            #pragma unroll
            for (int off = 1; off < 16; off <<= 1) l[r] += __shfl_xor(l[r], off);

        // ---- P -> LDS, then PV MFMAs ----
        #pragma unroll
        for (int kt = 0; kt < 16; ++kt)
            #pragma unroll
            for (int r = 0; r < 4; ++r)
                Pww[(quad*4 + r)*264 + kt*16 + ln16] = (__bf16)S[kt][r];

        floatx4 O0 = z4, O1 = z4;
        #pragma unroll
        for (int ks = 0; ks < 8; ++ks) {
            const bf16x8 Af = *(const bf16x8*)&Pww[ln16*264 + ks*32 + quad*8];
            const bf16x8 V0 = *(const bf16x8*)&VT[ln16*264 + ks*32 + quad*8];
            const bf16x8 V1 = *(const bf16x8*)&VT[(16 + ln16)*264 + ks*32 + quad*8];
            O0 = mfma16(Af, V0, O0);
            O1 = mfma16(Af, V1, O1);
        }

        // ---- normalize+gate -> fp16 repack in wave-private LDS ----
        _Float16* Po = (_Float16*)Pww;
        #pragma unroll
        for (int r = 0; r < 4; ++r) {
            const float inv = 1.0f / l[r];
            const int jrow = jrow0 + quad*4 + r;
            const float g0 = (float)gb[jrow*32 + ln16];
            const float g1 = (float)gb[jrow*32 + 16 + ln16];
            const float gate0 = 1.0f / (1.0f + __expf(-(g0 + bg0)));
            const float gate1 = 1.0f / (1.0f + __expf(-(g1 + bg1)));
            Po[(quad*4 + r)*264 + ln16]      = (_Float16)(O0[r] * inv * gate0);
            Po[(quad*4 + r)*264 + 16 + ln16] = (_Float16)(O1[r] * inv * gate1);
        }
        // contiguous 1KB-per-wave store (in-order DS pipe, wave-private)
        {
            const int rr = lane >> 2, cc = lane & 3;
            const halfx8 ov = *(const halfx8*)&Po[rr*264 + cc*8];
            *(halfx8*)&ogb[(size_t)(jrow0 + rr)*32 + cc*8] = ov;
        }
    }
}

// ---------------------------------------------------------------------------
// K4: output projection as f16 MFMA GEMM: out[(j*256+i)*128 + c] =
// sum_k og[(i*256+j), k] * woh[c, k] + bo[c], k = h*32+d over 4 head-slices.
// No LDS; A from og fp16 (coalesced), B from woh (L2-resident).
// ---------------------------------------------------------------------------
__global__ __launch_bounds__(256, 4) void outproj_kernel(
    const _Float16* __restrict__ og, const _Float16* __restrict__ woh,
    const float* __restrict__ bo, float* __restrict__ out)
{
    const int t = threadIdx.x, w = t >> 6, lane = t & 63;
    const int ln16 = lane & 15, quad = lane >> 4;
    const int wr = w >> 1, wc = w & 1;
    const int m_base = blockIdx.x * 128 + wr * 64;
    const int n_base = wc * 64;

    floatx4 Cf[4][4];
    const floatx4 z4 = {0.f, 0.f, 0.f, 0.f};
    #pragma unroll
    for (int mt = 0; mt < 4; ++mt)
        #pragma unroll
        for (int nt = 0; nt < 4; ++nt) Cf[mt][nt] = z4;

    #pragma unroll
    for (int ks = 0; ks < 4; ++ks) {   // ks = head
        halfx8 Af[4], Bf[4];
        #pragma unroll
        for (int mt = 0; mt < 4; ++mt)
            Af[mt] = *(const halfx8*)&og[(size_t)ks*2097152 + (size_t)(m_base + mt*16 + ln16)*32 + quad*8];
        #pragma unroll
        for (int nt = 0; nt < 4; ++nt)
            Bf[nt] = *(const halfx8*)&woh[(n_base + nt*16 + ln16)*128 + ks*32 + quad*8];
        #pragma unroll
        for (int mt = 0; mt < 4; ++mt)
            #pragma unroll
            for (int nt = 0; nt < 4; ++nt)
                Cf[mt][nt] = mfma16h(Af[mt], Bf[nt], Cf[mt][nt]);
    }

    float bov[4];
    #pragma unroll
    for (int nt = 0; nt < 4; ++nt) bov[nt] = bo[n_base + nt*16 + ln16];

    #pragma unroll
    for (int mt = 0; mt < 4; ++mt)
        #pragma unroll
        for (int r = 0; r < 4; ++r) {
            const int m = m_base + mt*16 + quad*4 + r;
            const size_t orow = (size_t)(m & 255) * 256 + (m >> 8);  // (j,i)
            #pragma unroll
            for (int nt = 0; nt < 4; ++nt)
                out[orow*128 + n_base + nt*16 + ln16] = Cf[mt][nt][r] + bov[nt];
        }
}

// ---------------------------------------------------------------------------
extern "C" void kernel_launch(void* const* d_in, const int* in_sizes, int n_in,
                              void* d_out, int out_size, void* d_ws, size_t ws_size,
                              hipStream_t stream) {
    const float* x     = (const float*)d_in[0];
    const float* mask  = (const float*)d_in[1];
    const float* lnw   = (const float*)d_in[2];
    const float* lnb   = (const float*)d_in[3];
    const float* wbias = (const float*)d_in[4];
    const float* wq    = (const float*)d_in[5];
    const float* wk    = (const float*)d_in[6];
    const float* wv    = (const float*)d_in[7];
    const float* wg    = (const float*)d_in[8];
    const float* bg    = (const float*)d_in[9];
    const float* wo    = (const float*)d_in[10];
    const float* bo    = (const float*)d_in[11];
    float* out = (float*)d_out;

    char* wsb = (char*)d_ws;
    __bf16*    xn   = (__bf16*)   (wsb);              // 16.78 MB
    float*     tbp  = (float*)    (wsb + 16777216);   //  1.05 MB (permuted)
    __bf16*    wTg  = (__bf16*)   (wsb + 17825792);   //  0.13 MB
    _Float16*  woh  = (_Float16*) (wsb + 17956864);   //  0.03 MB
    __bf16*    qbuf = (__bf16*)   (wsb + 17989632);   // 16.78 MB
    __bf16*    kbuf = (__bf16*)   (wsb + 34766848);   // 16.78 MB
    __bf16*    vbuf = (__bf16*)   (wsb + 51544064);   // 16.78 MB
    __bf16*    gbuf = (__bf16*)   (wsb + 68321280);   // 16.78 MB
    _Float16*  ogh  = (_Float16*) (wsb + 85098496);   // 16.78 MB (total ~102 MB)

    wt_kernel<<<40, 256, 0, stream>>>(wq, wk, wv, wg, wo, wTg, woh);
    ln_kernel<<<8192, 256, 0, stream>>>(x, lnw, lnb, wbias, xn, tbp);
    proj_kernel<<<dim3(512, 4), 256, 0, stream>>>(xn, wTg, qbuf, kbuf, vbuf, gbuf);
    attn_kernel<<<1024, 256, 0, stream>>>(tbp, mask, bg, qbuf, kbuf, vbuf, gbuf, ogh);
    outproj_kernel<<<512, 256, 0, stream>>>(ogh, woh, bo, out);
}